// Round 5
// baseline (1283.249 us; speedup 1.0000x reference)
//
#include <hip/hip_runtime.h>
#include <math.h>

// LSTM B=256, T=2048, D=H=64, OUT=8, fp32. One block (4 waves) per batch row.
// Round-11 = round-10 (k-split + readlane h-broadcast, 990 us) restructured
// to starve the shared LDS pipe and lighten the per-step barrier:
//  (1) x path moved OFF LDS: per step each wave needs only its 64 B k-slice
//      of x_t (wave-uniform). Two named register buffers (bA/bB) form a
//      2-step-deep global->VGPR prefetch pipeline (~2000 cy flight >> 900 cy
//      HBM latency). Addresses are pinned to VGPRs (asm "+v") so the loads
//      can't scalarize to s_load (which would poison the per-step lgkmcnt
//      drain). Compiler inserts counted vmcnt waits before consumption.
//  (2) per-step __syncthreads (vmcnt0+lgkmcnt0 drain) -> minimal exchange
//      sync: "s_waitcnt lgkmcnt(0); s_barrier" (P-write drained; prefetch
//      loads stay in flight across the barrier -- T4 discipline).
//  (3) xch/global_load_lds/chunk machinery deleted: DS ops drop 9->5
//      b128/wave/step; LDS 41.5K -> 8.5K.
// Round-10 post-mortem: readlane-vs-LDS h-broadcast was time-neutral at
// 990 us with VALUBusy 46->57% => step time pinned by DS-pipe occupancy +
// barrier drains, which is what (1)-(3) attack.

#define Hh 64
#define Tt 2048
#define Bb 256
#define OUTN 8

typedef float floatx4 __attribute__((ext_vector_type(4)));
typedef float floatx2 __attribute__((ext_vector_type(2)));

__device__ __forceinline__ float hsum4(floatx4 a) {
    floatx2 t = a.lo + a.hi;          // v_pk_add_f32
    return t.x + t.y;
}

// sigma(z) given the PRE-SCALED logit zp = -log2e * z
__device__ __forceinline__ float sigm2(float zp) {
    return __builtin_amdgcn_rcpf(1.0f + __builtin_amdgcn_exp2f(zp));
}

// One LSTM step. T_: timestep. PAR_: P-buffer parity (0/1). BUF_: register
// x-buffer holding this wave's k-slice of x_{T_+1}; reloaded with x_{T_+3}.
#define LSTM_STEP(T_, PAR_, BUF_)                                            \
  {                                                                          \
    /* ---- h-half FMA on carried accumulators (hv from readlanes) ---- */   \
    _Pragma("unroll")                                                        \
    for (int q = 0; q < 4; ++q) {                                            \
      floatx4 v = hv[q];                                                     \
      acc0 = __builtin_elementwise_fma(wh[0][q], v, acc0);                   \
      acc1 = __builtin_elementwise_fma(wh[1][q], v, acc1);                   \
      acc2 = __builtin_elementwise_fma(wh[2][q], v, acc2);                   \
      acc3 = __builtin_elementwise_fma(wh[3][q], v, acc3);                   \
    }                                                                        \
    floatx4 part;                                                            \
    part.x = hsum4(acc0); part.y = hsum4(acc1);                              \
    part.z = hsum4(acc2); part.w = hsum4(acc3);                              \
    *(floatx4*)&P[PAR_][wave][lane][0] = part;                               \
    /* minimal exchange sync: drain DS write, barrier; vmcnt NOT drained */  \
    asm volatile("s_waitcnt lgkmcnt(0)\n\ts_barrier" ::: "memory");          \
    /* ---- P-reads; latency covered by the register x-dot below ---- */     \
    floatx4 p0 = *(const floatx4*)&P[PAR_][0][lane][0];                      \
    floatx4 p1 = *(const floatx4*)&P[PAR_][1][lane][0];                      \
    floatx4 p2 = *(const floatx4*)&P[PAR_][2][lane][0];                      \
    floatx4 p3 = *(const floatx4*)&P[PAR_][3][lane][0];                      \
    /* ---- next-step x-dot from registers (compiler waits its vmcnt) ---- */\
    floatx4 n0, n1, n2, n3;                                                  \
    {                                                                        \
      floatx4 v = BUF_[0];                                                   \
      n0 = wx[0][0] * v; n1 = wx[1][0] * v;                                  \
      n2 = wx[2][0] * v; n3 = wx[3][0] * v;                                  \
    }                                                                        \
    _Pragma("unroll")                                                        \
    for (int q = 1; q < 4; ++q) {                                            \
      floatx4 v = BUF_[q];                                                   \
      n0 = __builtin_elementwise_fma(wx[0][q], v, n0);                       \
      n1 = __builtin_elementwise_fma(wx[1][q], v, n1);                       \
      n2 = __builtin_elementwise_fma(wx[2][q], v, n2);                       \
      n3 = __builtin_elementwise_fma(wx[3][q], v, n3);                       \
    }                                                                        \
    /* ---- reissue prefetch: x_{T_+3} k-slice -> BUF_ (2-step flight) ---- */\
    {                                                                        \
      int tn = (T_) + 3; if (tn > Tt - 1) tn = Tt - 1;                       \
      unsigned voff = (unsigned)(tn * (Hh * 4) + (kb16 << 2));               \
      asm volatile("" : "+v"(voff));          /* force VGPR addr path */     \
      const floatx4* xp = (const floatx4*)((const char*)xb + voff);          \
      _Pragma("unroll")                                                      \
      for (int q = 0; q < 4; ++q) BUF_[q] = xp[q];                           \
    }                                                                        \
    /* ---- reduce + activations (pre-scaled logits) + c/h update ---- */    \
    floatx4 z = bias4 + ((p0 + p1) + (p2 + p3));                             \
    float i_ = sigm2(z.x);                                                   \
    float f_ = sigm2(z.y);                                                   \
    float g_ = 2.0f * sigm2(z.z) - 1.0f;       /* tanh via 2*sigma-1 */      \
    float o_ = sigm2(z.w);                                                   \
    c = __builtin_fmaf(f_, c, i_ * g_);                                      \
    float th = 2.0f * sigm2(SC2 * c) - 1.0f;                                 \
    hj = o_ * th;                                                            \
    /* ---- h broadcast via readlane (wave-uniform indices, no LDS) ---- */  \
    {                                                                        \
      const int hbits = __float_as_int(hj);                                  \
      _Pragma("unroll")                                                      \
      for (int q = 0; q < 4; ++q) {                                          \
        _Pragma("unroll")                                                    \
        for (int e = 0; e < 4; ++e) {                                        \
          hv[q][e] = __int_as_float(                                         \
              __builtin_amdgcn_readlane(hbits, kb16 + 4 * q + e));           \
        }                                                                    \
      }                                                                      \
    }                                                                        \
    acc0 = n0; acc1 = n1; acc2 = n2; acc3 = n3;                              \
  }

__global__ __launch_bounds__(256, 1)
void lstm_fused_kernel(const float* __restrict__ x,
                       const float* __restrict__ w_ih,
                       const float* __restrict__ w_hh,
                       const float* __restrict__ b_ih,
                       const float* __restrict__ b_hh,
                       const float* __restrict__ fc_w,
                       const float* __restrict__ fc_b,
                       float* __restrict__ out)
{
    __shared__ __align__(16) float P[2][4][Hh][4];   // parity x wave x j x gate
    __shared__ __align__(16) float h_s[Hh];          // epilogue only

    const int tid  = threadIdx.x;
    const int b    = blockIdx.x;
    const int wave = tid >> 6;     // k-slice index
    const int lane = tid & 63;     // hidden unit j

    const float* xb = x + (size_t)b * Tt * Hh;

    const float SC1 = -1.44269504088896340736f;   // -log2(e)
    const float SC2 = -2.88539008177792681472f;   // -2*log2(e)

    // ---- weights: lane j, gate g -> row 64g+j, cols [16w,16w+16), scaled ----
    floatx4 wx[4][4], wh[4][4];    // 32 float4 = 128 regs, pinned
    const int kb16 = 16 * wave;
    {
        #pragma unroll
        for (int g = 0; g < 4; ++g) {
            const float sc = (g == 2) ? SC2 : SC1;
            const floatx4* pi = (const floatx4*)(w_ih + (size_t)((g << 6) + lane) * Hh + kb16);
            const floatx4* ph = (const floatx4*)(w_hh + (size_t)((g << 6) + lane) * Hh + kb16);
            #pragma unroll
            for (int q = 0; q < 4; ++q) { wx[g][q] = pi[q] * sc; wh[g][q] = ph[q] * sc; }
        }
        #pragma unroll
        for (int g = 0; g < 4; ++g)
            #pragma unroll
            for (int q = 0; q < 4; ++q)
                asm volatile("" : "+v"(wx[g][q]), "+v"(wh[g][q]));
    }
    floatx4 bias4;
    bias4.x = (b_ih[lane]       + b_hh[lane])       * SC1;   // i
    bias4.y = (b_ih[64 + lane]  + b_hh[64 + lane])  * SC1;   // f
    bias4.z = (b_ih[128 + lane] + b_hh[128 + lane]) * SC2;   // g (tanh)
    bias4.w = (b_ih[192 + lane] + b_hh[192 + lane]) * SC1;   // o

    // ---- x prefetch pipeline: prime x_0 (temp), issue x_1->bA, x_2->bB ----
    floatx4 bA[4], bB[4];
    floatx4 x0[4];
    {
        unsigned v0 = (unsigned)(kb16 << 2);
        asm volatile("" : "+v"(v0));
        const floatx4* xp0 = (const floatx4*)((const char*)xb + v0);
        #pragma unroll
        for (int q = 0; q < 4; ++q) x0[q] = xp0[q];

        unsigned v1 = (unsigned)(1 * (Hh * 4) + (kb16 << 2));
        asm volatile("" : "+v"(v1));
        const floatx4* xp1 = (const floatx4*)((const char*)xb + v1);
        #pragma unroll
        for (int q = 0; q < 4; ++q) bA[q] = xp1[q];

        unsigned v2 = (unsigned)(2 * (Hh * 4) + (kb16 << 2));
        asm volatile("" : "+v"(v2));
        const floatx4* xp2 = (const floatx4*)((const char*)xb + v2);
        #pragma unroll
        for (int q = 0; q < 4; ++q) bB[q] = xp2[q];
    }

    float c = 0.0f;                // lane j of every wave: c[j] (replicated)
    float hj = 0.0f;               // h[j] for j = lane (replicated per wave)
    floatx4 hv[4];                 // this wave's k-slice of h, via readlane
    #pragma unroll
    for (int q = 0; q < 4; ++q) hv[q] = (floatx4)(0.0f);     // h_0 = 0

    // ---- prime accumulators with x_0's contribution ----
    floatx4 acc0, acc1, acc2, acc3;
    {
        floatx4 v = x0[0];
        acc0 = wx[0][0] * v; acc1 = wx[1][0] * v;
        acc2 = wx[2][0] * v; acc3 = wx[3][0] * v;
        #pragma unroll
        for (int q = 1; q < 4; ++q) {
            v = x0[q];
            acc0 = __builtin_elementwise_fma(wx[0][q], v, acc0);
            acc1 = __builtin_elementwise_fma(wx[1][q], v, acc1);
            acc2 = __builtin_elementwise_fma(wx[2][q], v, acc2);
            acc3 = __builtin_elementwise_fma(wx[3][q], v, acc3);
        }
    }

    // ---- main loop: 2 steps per iteration (parity-named buffers) ----
    for (int t = 0; t < Tt; t += 2) {
        LSTM_STEP(t,     0, bA)
        LSTM_STEP(t + 1, 1, bB)
    }

    // ---- epilogue: out[b] = h_T @ fc_w^T + fc_b ----
    if (wave == 0) h_s[lane] = hj;
    __syncthreads();
    if (tid < OUTN) {
        float acc = fc_b[tid];
        #pragma unroll
        for (int j = 0; j < Hh; ++j) acc += fc_w[tid * Hh + j] * h_s[j];
        out[b * OUTN + tid] = acc;
    }
}

extern "C" void kernel_launch(void* const* d_in, const int* in_sizes, int n_in,
                              void* d_out, int out_size, void* d_ws, size_t ws_size,
                              hipStream_t stream) {
    const float* x    = (const float*)d_in[0];
    const float* w_ih = (const float*)d_in[1];
    const float* w_hh = (const float*)d_in[2];
    const float* b_ih = (const float*)d_in[3];
    const float* b_hh = (const float*)d_in[4];
    const float* fc_w = (const float*)d_in[5];
    const float* fc_b = (const float*)d_in[6];
    float* out = (float*)d_out;

    lstm_fused_kernel<<<Bb, 256, 0, stream>>>(x, w_ih, w_hh, b_ih, b_hh,
                                              fc_w, fc_b, out);
}